// Round 17
// baseline (6603.802 us; speedup 1.0000x reference)
//
#include <hip/hip_runtime.h>
#include <math.h>

#define HH 512
#define EE 256
#define BB 64
#define TT 64
#define VV 32000
#define H3 1536
#define TDEC 63

typedef _Float16 v2h __attribute__((ext_vector_type(2)));
typedef _Float16 v4h __attribute__((ext_vector_type(4)));
typedef _Float16 v8h __attribute__((ext_vector_type(8)));
typedef float v4f __attribute__((ext_vector_type(4)));

__device__ __forceinline__ float sigm(float x) { return 1.f / (1.f + expf(-x)); }

// ---------------- embedding gather: x[b*T+t][e] = emb[src[b*T+t]][e]
__global__ void k_embed(const int* __restrict__ src, const float* __restrict__ emb,
                        float* __restrict__ x) {
    int idx = blockIdx.x * 256 + threadIdx.x;      // B*T*E = 1048576
    int row = idx >> 8;
    int e = idx & 255;
    x[idx] = emb[src[row] * EE + e];
}

// ---------------- decoder-token embedding gather: XTOK[t*64+b] = emb_en[tok(b,t)]
__global__ void k_embtok(const int* __restrict__ trg, const float* __restrict__ emb,
                         float* __restrict__ x) {
    int idx = blockIdx.x * 256 + threadIdx.x;      // 4096*256 = 1048576
    int row = idx >> 8;
    int e = idx & 255;
    int t = row >> 6, b = row & 63;
    int tok = (t == 0) ? 1 : ((t < 63) ? trg[b * TT + t] : 0);
    x[idx] = emb[tok * EE + e];
}

__global__ void k_zero1536(float* __restrict__ z) {
    int i = blockIdx.x * 256 + threadIdx.x;
    if (i < 1536) z[i] = 0.f;
}

// ---------------- W (512 x N fp32) -> WT (N x 512 f16), 64x64 LDS tile transpose
__global__ __launch_bounds__(256) void k_cvt_t(const float* __restrict__ W,
                                               _Float16* __restrict__ WT, int N) {
    __shared__ _Float16 tile[64][65];
    int n0 = blockIdx.x * 64, k0 = blockIdx.y * 64;
    int t = threadIdx.x;
#pragma unroll
    for (int i = 0; i < 16; ++i) {
        int idx = i * 256 + t;
        int r = idx >> 6, c = idx & 63;     // r = k-local, c = n-local
        tile[r][c] = (_Float16)W[(size_t)(k0 + r) * N + n0 + c];
    }
    __syncthreads();
#pragma unroll
    for (int i = 0; i < 16; ++i) {
        int idx = i * 256 + t;
        int r = idx >> 6, c = idx & 63;     // r = n-local, c = k-local
        WT[(size_t)(n0 + r) * 512 + k0 + c] = tile[c][r];
    }
}

// ---------------- ENCWH [b*64+s][1536] f16 -> ENCWT [b][j][s] f16 (s-contiguous)
__global__ __launch_bounds__(256) void k_trans_encw(const _Float16* __restrict__ S,
                                                    _Float16* __restrict__ D) {
    __shared__ _Float16 tile[64][65];
    int j0 = blockIdx.x * 64;
    int b = blockIdx.y;
    int t = threadIdx.x;
#pragma unroll
    for (int i = 0; i < 16; ++i) {
        int idx = i * 256 + t;
        int r = idx >> 6, c = idx & 63;     // r = s, c = j-local
        tile[r][c] = S[((size_t)(b * TT + r)) * H3 + j0 + c];
    }
    __syncthreads();
#pragma unroll
    for (int i = 0; i < 16; ++i) {
        int idx = i * 256 + t;
        int r = idx >> 6, c = idx & 63;     // r = j-local, c = s
        D[((size_t)b * H3 + j0 + r) * 64 + c] = tile[c][r];
    }
}

// ---------------- 128x128 fp32 GEMM + bias, 8x8 micro-tile (split 64+64), R5-proven
__global__ __launch_bounds__(256) void k_gemm128_bias(
    const float* __restrict__ A, const float* __restrict__ W,
    const float* __restrict__ bias, float* __restrict__ C,
    int N, int K) {
    __shared__ float As[8][128];
    __shared__ float Bs[8][128];
    int row0 = blockIdx.y * 128, col0 = blockIdx.x * 128;
    int tid = threadIdx.x;
    int tx = tid & 15, ty = tid >> 4;
    int ar = tid >> 1, aq = tid & 1;
    int bkk = tid >> 5, bc4 = tid & 31;
    float acc[2][2][4][4] = {};
    for (int k0 = 0; k0 < K; k0 += 8) {
        float4 av = *(const float4*)&A[(size_t)(row0 + ar) * K + k0 + aq * 4];
        float4 bv = *(const float4*)&W[(size_t)(k0 + bkk) * N + col0 + bc4 * 4];
        As[aq * 4 + 0][ar] = av.x;
        As[aq * 4 + 1][ar] = av.y;
        As[aq * 4 + 2][ar] = av.z;
        As[aq * 4 + 3][ar] = av.w;
        *(float4*)&Bs[bkk][bc4 * 4] = bv;
        __syncthreads();
#pragma unroll
        for (int kk = 0; kk < 8; ++kk) {
            float4 a0 = *(const float4*)&As[kk][ty * 4];
            float4 a1 = *(const float4*)&As[kk][64 + ty * 4];
            float4 b0 = *(const float4*)&Bs[kk][tx * 4];
            float4 b1 = *(const float4*)&Bs[kk][64 + tx * 4];
            float a_[2][4] = {{a0.x, a0.y, a0.z, a0.w}, {a1.x, a1.y, a1.z, a1.w}};
            float b_[2][4] = {{b0.x, b0.y, b0.z, b0.w}, {b1.x, b1.y, b1.z, b1.w}};
#pragma unroll
            for (int rh = 0; rh < 2; ++rh)
#pragma unroll
                for (int i = 0; i < 4; ++i)
#pragma unroll
                    for (int ch = 0; ch < 2; ++ch)
#pragma unroll
                        for (int j = 0; j < 4; ++j)
                            acc[rh][ch][i][j] = fmaf(a_[rh][i], b_[ch][j], acc[rh][ch][i][j]);
        }
        __syncthreads();
    }
#pragma unroll
    for (int rh = 0; rh < 2; ++rh)
#pragma unroll
        for (int i = 0; i < 4; ++i) {
            int row = row0 + rh * 64 + ty * 4 + i;
#pragma unroll
            for (int ch = 0; ch < 2; ++ch) {
                int c = col0 + ch * 64 + tx * 4;
                float4 bv = *(const float4*)&bias[c];
                float4 o;
                o.x = acc[rh][ch][i][0] + bv.x;
                o.y = acc[rh][ch][i][1] + bv.y;
                o.z = acc[rh][ch][i][2] + bv.z;
                o.w = acc[rh][ch][i][3] + bv.w;
                *(float4*)&C[(size_t)row * N + c] = o;
            }
        }
}

// ---------------- same GEMM, f16 output (for decoder operand precompute)
__global__ __launch_bounds__(256) void k_gemm128_bias_h(
    const float* __restrict__ A, const float* __restrict__ W,
    const float* __restrict__ bias, _Float16* __restrict__ C,
    int N, int K) {
    __shared__ float As[8][128];
    __shared__ float Bs[8][128];
    int row0 = blockIdx.y * 128, col0 = blockIdx.x * 128;
    int tid = threadIdx.x;
    int tx = tid & 15, ty = tid >> 4;
    int ar = tid >> 1, aq = tid & 1;
    int bkk = tid >> 5, bc4 = tid & 31;
    float acc[2][2][4][4] = {};
    for (int k0 = 0; k0 < K; k0 += 8) {
        float4 av = *(const float4*)&A[(size_t)(row0 + ar) * K + k0 + aq * 4];
        float4 bv = *(const float4*)&W[(size_t)(k0 + bkk) * N + col0 + bc4 * 4];
        As[aq * 4 + 0][ar] = av.x;
        As[aq * 4 + 1][ar] = av.y;
        As[aq * 4 + 2][ar] = av.z;
        As[aq * 4 + 3][ar] = av.w;
        *(float4*)&Bs[bkk][bc4 * 4] = bv;
        __syncthreads();
#pragma unroll
        for (int kk = 0; kk < 8; ++kk) {
            float4 a0 = *(const float4*)&As[kk][ty * 4];
            float4 a1 = *(const float4*)&As[kk][64 + ty * 4];
            float4 b0 = *(const float4*)&Bs[kk][tx * 4];
            float4 b1 = *(const float4*)&Bs[kk][64 + tx * 4];
            float a_[2][4] = {{a0.x, a0.y, a0.z, a0.w}, {a1.x, a1.y, a1.z, a1.w}};
            float b_[2][4] = {{b0.x, b0.y, b0.z, b0.w}, {b1.x, b1.y, b1.z, b1.w}};
#pragma unroll
            for (int rh = 0; rh < 2; ++rh)
#pragma unroll
                for (int i = 0; i < 4; ++i)
#pragma unroll
                    for (int ch = 0; ch < 2; ++ch)
#pragma unroll
                        for (int j = 0; j < 4; ++j)
                            acc[rh][ch][i][j] = fmaf(a_[rh][i], b_[ch][j], acc[rh][ch][i][j]);
        }
        __syncthreads();
    }
#pragma unroll
    for (int rh = 0; rh < 2; ++rh)
#pragma unroll
        for (int i = 0; i < 4; ++i) {
            int row = row0 + rh * 64 + ty * 4 + i;
#pragma unroll
            for (int ch = 0; ch < 2; ++ch) {
                int c = col0 + ch * 64 + tx * 4;
                float4 bv = *(const float4*)&bias[c];
                v4h o;
                o[0] = (_Float16)(acc[rh][ch][i][0] + bv.x);
                o[1] = (_Float16)(acc[rh][ch][i][1] + bv.y);
                o[2] = (_Float16)(acc[rh][ch][i][2] + bv.z);
                o[3] = (_Float16)(acc[rh][ch][i][3] + bv.w);
                *(v4h*)&C[(size_t)row * N + c] = o;
            }
        }
}

// ---------------- GRU recurrent step, 4-batch-shared / 256-block / split-k-16 (R7-proven)
struct GruP {
    const float* xg;     // (B*T, 3H)
    const float* hb;     // carried h base (nullptr -> zeros)
    float* y;
    const float* U;      // (H, 3H)
    const float* b1;     // (3H)
    int t, tprev, ystride, yoff;
};

__global__ __launch_bounds__(512) void k_gru5(GruP p0, GruP p1, const int* __restrict__ src,
                                              int nblk) {
    GruP p = (blockIdx.x < nblk) ? p0 : p1;
    int blk = (blockIdx.x < nblk) ? blockIdx.x : blockIdx.x - nblk;
    int bg = blk >> 4;                 // batches bg*4 .. bg*4+3
    int ic = blk & 15;                 // 32-col chunk
    int tid = threadIdx.x;
    int c = tid & 31, kh = tid >> 5;   // kh 0..15, each owns 32 k
    int i = ic * 32 + c;
    __shared__ float hs[4][512];
    __shared__ float ps[12][512];      // [gate*4+b][kh*32+c] (transposed: conflict-free)
    for (int j = tid; j < 2048; j += 512) {
        int bl = j >> 9, k = j & 511;
        hs[bl][k] = p.hb ? p.hb[(size_t)((bg * 4 + bl) * TT + p.tprev) * p.ystride + p.yoff + k]
                         : 0.f;
    }
    __syncthreads();
    float az[4] = {}, ar[4] = {}, ah[4] = {};
    const float* Up = p.U + (size_t)(kh * 32) * H3 + i;
    int ks0 = kh * 32;
#pragma unroll 8
    for (int k = 0; k < 32; ++k) {
        const float* Ur = Up + k * H3;
        float uz = Ur[0], ur = Ur[512], uh = Ur[1024];
#pragma unroll
        for (int b = 0; b < 4; ++b) {
            float h = hs[b][ks0 + k];                 // LDS broadcast within kh-group
            az[b] = fmaf(h, uz, az[b]);
            ar[b] = fmaf(h, ur, ar[b]);
            ah[b] = fmaf(h, uh, ah[b]);
        }
    }
#pragma unroll
    for (int b = 0; b < 4; ++b) {
        ps[b][tid] = az[b];
        ps[4 + b][tid] = ar[b];
        ps[8 + b][tid] = ah[b];
    }
    __syncthreads();
    if (tid < 128) {
        int b = tid >> 5, cc = tid & 31;
        float AZ = 0.f, AR = 0.f, AH = 0.f;
        for (int q = 0; q < 16; ++q) {
            AZ += ps[b][q * 32 + cc];
            AR += ps[4 + b][q * 32 + cc];
            AH += ps[8 + b][q * 32 + cc];
        }
        int ii = ic * 32 + cc;
        int row = (bg * 4 + b) * TT + p.t;
        const float* xr = p.xg + (size_t)row * H3;
        float z = sigm(xr[ii] + AZ + p.b1[ii]);
        float r = sigm(xr[512 + ii] + AR + p.b1[512 + ii]);
        float hc = sigm(xr[1024 + ii] + r * (AH + p.b1[1024 + ii]));
        float hp = hs[b][ii];
        float hn = (src[row] != 0) ? (z * hp + (1.f - z) * hc) : hp;
        p.y[(size_t)row * p.ystride + p.yoff + ii] = hn;
    }
}

// ---------------- pipelined encoder step: m-phase (xg precomputed) || t-phase (xg fused)
struct EncP {
    const float* xg;     // m-phase: precomputed gates; t-phase: nullptr (fused)
    const float* xseq;   // t-phase: input sequence (B*T, 512)
    const float* xW;     // t-phase: W (512, 3H)
    const float* xb0;    // t-phase: x-bias (row 0 of b)
    float* y;            // output sequence
    const float* U;      // (H, 3H)
    const float* b1;     // recurrent bias (row 1)
    int t;               // timestep this stage (-1 = inactive)
    int ystride, yoff;
};

__global__ __launch_bounds__(512) void k_enc_step(EncP pm, EncP pt, const int* __restrict__ src) {
    EncP p = (blockIdx.x < 256) ? pm : pt;
    if (p.t < 0) return;
    int blk = blockIdx.x & 255;
    int bg = blk >> 4, ic = blk & 15;
    int tid = threadIdx.x;
    int c = tid & 31, kh = tid >> 5;
    int i = ic * 32 + c;
    __shared__ float hs[4][512];
    __shared__ float xs[4][512];
    __shared__ float ps[16][512];
    bool fused = (p.xg == nullptr);
    int tprev = p.t - 1;
    for (int j = tid; j < 2048; j += 512) {
        int bl = j >> 9, k = j & 511;
        hs[bl][k] = (tprev < 0) ? 0.f
            : p.y[(size_t)((bg * 4 + bl) * TT + tprev) * p.ystride + p.yoff + k];
        if (fused)
            xs[bl][k] = p.xseq[(size_t)((bg * 4 + bl) * TT + p.t) * 512 + k];
    }
    __syncthreads();
    float az[4] = {}, ar[4] = {}, ahU[4] = {}, ahW[4] = {};
    int ks0 = kh * 32;
    {
        const float* Up = p.U + (size_t)ks0 * H3 + i;
#pragma unroll 8
        for (int k = 0; k < 32; ++k) {
            const float* Ur = Up + k * H3;
            float uz = Ur[0], ur = Ur[512], uh = Ur[1024];
#pragma unroll
            for (int b = 0; b < 4; ++b) {
                float h = hs[b][ks0 + k];
                az[b] = fmaf(h, uz, az[b]);
                ar[b] = fmaf(h, ur, ar[b]);
                ahU[b] = fmaf(h, uh, ahU[b]);
            }
        }
    }
    if (fused) {
        const float* Wp = p.xW + (size_t)ks0 * H3 + i;
#pragma unroll 8
        for (int k = 0; k < 32; ++k) {
            const float* Wr = Wp + k * H3;
            float wz = Wr[0], wr = Wr[512], wh = Wr[1024];
#pragma unroll
            for (int b = 0; b < 4; ++b) {
                float x = xs[b][ks0 + k];
                az[b] = fmaf(x, wz, az[b]);
                ar[b] = fmaf(x, wr, ar[b]);
                ahW[b] = fmaf(x, wh, ahW[b]);
            }
        }
    }
#pragma unroll
    for (int b = 0; b < 4; ++b) {
        ps[b][tid] = az[b];
        ps[4 + b][tid] = ar[b];
        ps[8 + b][tid] = ahU[b];
        ps[12 + b][tid] = ahW[b];
    }
    __syncthreads();
    if (tid < 128) {
        int b = tid >> 5, cc = tid & 31;
        float AZ = 0.f, AR = 0.f, AHU = 0.f, AHW = 0.f;
        for (int q = 0; q < 16; ++q) {
            AZ += ps[b][q * 32 + cc];
            AR += ps[4 + b][q * 32 + cc];
            AHU += ps[8 + b][q * 32 + cc];
            AHW += ps[12 + b][q * 32 + cc];
        }
        int ii = ic * 32 + cc;
        int row = (bg * 4 + b) * TT + p.t;
        float xz, xr_, xh;
        if (fused) {
            xz = p.xb0[ii];
            xr_ = p.xb0[512 + ii];
            xh = AHW + p.xb0[1024 + ii];
        } else {
            const float* xr = p.xg + (size_t)row * H3;
            xz = xr[ii];
            xr_ = xr[512 + ii];
            xh = xr[1024 + ii];
        }
        float z = sigm(xz + AZ + p.b1[ii]);
        float r = sigm(xr_ + AR + p.b1[512 + ii]);
        float hc = sigm(xh + r * (AHU + p.b1[1024 + ii]));
        float hp = hs[b][ii];
        float hn = (src[row] != 0) ? (z * hp + (1.f - z) * hc) : hp;
        p.y[(size_t)row * p.ystride + p.yoff + ii] = hn;
    }
}

// ---------------- decoder, ALL 63 steps; lane-cooperative coalesced dot-products
// block = batch, 8 waves. A: wave-wide rows of aW2T; C: 8-lane rows of ENCWT.
__global__ __launch_bounds__(512) void k_dec_all3(
    const _Float16* __restrict__ keysh, const float* __restrict__ enc,
    const _Float16* __restrict__ aW2T, const float* __restrict__ ab2,
    const float* __restrict__ aV, const float* __restrict__ abV,
    const _Float16* __restrict__ ENCWT, const _Float16* __restrict__ EMBWh,
    const float* __restrict__ b1, _Float16* __restrict__ HMATH) {
    int b = blockIdx.x;
    int tid = threadIdx.x;
    int lane = tid & 63, wv = tid >> 6;
    __shared__ float hsh[HH];
    __shared__ float qs[HH];
    __shared__ float sc[TT];
    __shared__ float pre[H3];
    hsh[tid] = enc[((size_t)(b * TT + 63)) * HH + tid];   // h0 = enc[b][T-1]
    __syncthreads();
    float bz = b1[tid], br_ = b1[512 + tid], bh = b1[1024 + tid];
    for (int t = 0; t < TDEC; ++t) {
        // ---- phase A: q[n] for n in [wv*64, wv*64+64): full-wave coalesced row reads
        {
            float4 h0 = *(const float4*)&hsh[lane * 8];
            float4 h1 = *(const float4*)&hsh[lane * 8 + 4];
            int n0 = wv * 64;
#pragma unroll 2
            for (int nn = 0; nn < 64; nn += 2) {
                v8h w0 = *(const v8h*)(aW2T + (size_t)(n0 + nn) * HH + lane * 8);
                v8h w1 = *(const v8h*)(aW2T + (size_t)(n0 + nn + 1) * HH + lane * 8);
                float a0 = h0.x * (float)w0[0] + h0.y * (float)w0[1]
                         + h0.z * (float)w0[2] + h0.w * (float)w0[3]
                         + h1.x * (float)w0[4] + h1.y * (float)w0[5]
                         + h1.z * (float)w0[6] + h1.w * (float)w0[7];
                float a1 = h0.x * (float)w1[0] + h0.y * (float)w1[1]
                         + h0.z * (float)w1[2] + h0.w * (float)w1[3]
                         + h1.x * (float)w1[4] + h1.y * (float)w1[5]
                         + h1.z * (float)w1[6] + h1.w * (float)w1[7];
#pragma unroll
                for (int o = 1; o < 64; o <<= 1) {
                    a0 += __shfl_xor(a0, o);
                    a1 += __shfl_xor(a1, o);
                }
                if (lane == 0) {
                    qs[n0 + nn] = a0 + ab2[n0 + nn];
                    qs[n0 + nn + 1] = a1 + ab2[n0 + nn + 1];
                }
            }
        }
        __syncthreads();
        // ---- phase B: scores, 8 parts x 64 h, vectorized keys reads
        {
            int s = tid >> 3, part = tid & 7;
            const v8h* kr = (const v8h*)(keysh + (size_t)(b * TT + s) * HH + part * 64);
            const float* qp = qs + part * 64;
            const float* avp = aV + part * 64;
            float p = 0.f;
#pragma unroll
            for (int h8 = 0; h8 < 8; ++h8) {
                v8h kv = kr[h8];
#pragma unroll
                for (int u = 0; u < 8; ++u)
                    p += tanhf((float)kv[u] + qp[h8 * 8 + u]) * avp[h8 * 8 + u];
            }
            p += __shfl_down(p, 1);
            p += __shfl_down(p, 2);
            p += __shfl_down(p, 4);
            if (part == 0) sc[s] = p + abV[0];
        }
        __syncthreads();
        if (tid < 64) {
            float v = sc[tid];
            float m = v;
            for (int o = 1; o < 64; o <<= 1) m = fmaxf(m, __shfl_xor(m, o));
            float e = expf(v - m);
            float su = e;
            for (int o = 1; o < 64; o <<= 1) su += __shfl_xor(su, o);
            sc[tid] = e / su;
        }
        __syncthreads();
        // ---- phase C: pre[j] via 8-lane coalesced ENCWT rows + EMBW
        {
            int jl = lane >> 3, sl = lane & 7;       // 8 outputs/wave-group, k-slice sl
            const float* sp = sc + sl * 8;
#pragma unroll
            for (int g = 0; g < 3; ++g) {
                int j = g * 512 + wv * 64;           // this wave's 64 outputs, 8 at a time
#pragma unroll
                for (int jj = 0; jj < 64; jj += 8) {
                    int jo = j + jj + jl;
                    v8h ev = *(const v8h*)(ENCWT + ((size_t)b * H3 + jo) * 64 + sl * 8);
                    float pg = sp[0] * (float)ev[0] + sp[1] * (float)ev[1]
                             + sp[2] * (float)ev[2] + sp[3] * (float)ev[3]
                             + sp[4] * (float)ev[4] + sp[5] * (float)ev[5]
                             + sp[6] * (float)ev[6] + sp[7] * (float)ev[7];
                    pg += __shfl_down(pg, 1);
                    pg += __shfl_down(pg, 2);
                    pg += __shfl_down(pg, 4);
                    if (sl == 0) pre[jo] = pg;
                }
            }
        }
        __syncthreads();
        // ---- gates (h_prev = 0): hn = (1-z)*hc; carry h in LDS
        {
            const _Float16* mr = EMBWh + (size_t)(t * BB + b) * H3;
            float z = sigm(pre[tid] + (float)mr[tid] + bz);
            float r = sigm(pre[512 + tid] + (float)mr[512 + tid] + br_);
            float hc = sigm(pre[1024 + tid] + (float)mr[1024 + tid] + r * bh);
            float hn = (1.f - z) * hc;
            HMATH[((size_t)t * BB + b) * HH + tid] = (_Float16)hn;
            hsh[tid] = hn;
        }
        __syncthreads();
    }
}

// ---------------- logits GEMM via MFMA f16, 256x128 tile, XOR-swizzled LDS + fused LSE
__global__ __launch_bounds__(512) void k_gemm256_ce_m(
    const _Float16* __restrict__ Ah, const _Float16* __restrict__ WT,
    const float* __restrict__ bias, const int* __restrict__ trg,
    float* __restrict__ pmax, float* __restrict__ psum, float* __restrict__ tgtl) {
    __shared__ v2h As[256][20];     // 4 chunks of 16B per row, XOR-swizzled by row&3
    __shared__ v2h Bs[128][20];
    __shared__ float pm[256][2];
    __shared__ float ps[256][2];
    const v2h* A2 = (const v2h*)Ah;
    const v2h* W2 = (const v2h*)WT;
    int row0 = blockIdx.y * 256, col0 = blockIdx.x * 128;
    int tid = threadIdx.x;
    int l = tid & 63, wv = tid >> 6;
    int wr = wv >> 1, wc = wv & 1;           // 4 wave-rows x 2 wave-cols
    int lr = l & 15, kb = l >> 4;            // frag lane, k-block
    int sr = tid >> 1, sh = tid & 1;         // A staging: row 0..255, half
    int br = (tid & 255) >> 1, bh = tid & 1; // B staging (tid<256): row 0..127, half
    int arow = row0 + sr;
    if (arow > 4031) arow = 4031;            // clamp pad rows
    v4f acc[4][4];
#pragma unroll
    for (int i = 0; i < 4; ++i)
#pragma unroll
        for (int j = 0; j < 4; ++j) acc[i][j] = (v4f){0.f, 0.f, 0.f, 0.f};
    for (int k0 = 0; k0 < 256; k0 += 16) {   // k0 in v2h units; 32 f16 per step
        const v8h* agp = (const v8h*)(A2 + (size_t)arow * 256 + k0 + sh * 8);
        v8h av0 = agp[0], av1 = agp[1];
        v8h bv0, bv1;
        if (tid < 256) {
            const v8h* bgp = (const v8h*)(W2 + (size_t)(col0 + br) * 256 + k0 + bh * 8);
            bv0 = bgp[0];
            bv1 = bgp[1];
        }
        __syncthreads();                     // prev-iter fragment reads done
        int ca0 = (sh * 2) ^ (sr & 3), ca1 = (sh * 2 + 1) ^ (sr & 3);
        *(v8h*)&As[sr][ca0 * 4] = av0;
        *(v8h*)&As[sr][ca1 * 4] = av1;
        if (tid < 256) {
            int cb0 = (bh * 2) ^ (br & 3), cb1 = (bh * 2 + 1) ^ (br & 3);
            *(v8h*)&Bs[br][cb0 * 4] = bv0;
            *(v8h*)&Bs[br][cb1 * 4] = bv1;
        }
        __syncthreads();
        v8h af[4], bf[4];
#pragma unroll
        for (int f = 0; f < 4; ++f) {
            int ra = wr * 64 + f * 16 + lr;
            int rb = wc * 64 + f * 16 + lr;
            af[f] = *(const v8h*)&As[ra][(kb ^ (ra & 3)) * 4];
            bf[f] = *(const v8h*)&Bs[rb][(kb ^ (rb & 3)) * 4];
        }
#pragma unroll
        for (int fr = 0; fr < 4; ++fr)
#pragma unroll
            for (int fc = 0; fc < 4; ++fc)
                acc[fr][fc] = __builtin_amdgcn_mfma_f32_16x16x32_f16(
                    af[fr], bf[fc], acc[fr][fc], 0, 0, 0);
    }
    // epilogue: C/D map col=lane&15, row=(lane>>4)*4+reg (guide-verified)
    float bv[4];
#pragma unroll
    for (int fc = 0; fc < 4; ++fc) bv[fc] = bias[col0 + wc * 64 + fc * 16 + lr];
#pragma unroll
    for (int fr = 0; fr < 4; ++fr) {
#pragma unroll
        for (int ri = 0; ri < 4; ++ri) {
            int rl = wr * 64 + fr * 16 + kb * 4 + ri;
            int rg = row0 + rl;
            int tdec = rg >> 6, bq = rg & 63;
            int tgt = (rg < 4032) ? trg[bq * TT + tdec + 1] : -1;
            float vv[4];
            float lm = -1e30f;
#pragma unroll
            for (int fc = 0; fc < 4; ++fc) {
                int c = col0 + wc * 64 + fc * 16 + lr;
                float v = acc[fr][fc][ri] + bv[fc];
                vv[fc] = v;
                lm = fmaxf(lm, v);
                if (c == tgt) tgtl[rg] = v;
            }
            float lsum = 0.f;
#pragma unroll
            for (int fc = 0; fc < 4; ++fc) lsum += expf(vv[fc] - lm);
            // online-merge across the 16 col-lanes (same rows)
            for (int o = 1; o < 16; o <<= 1) {
                float m2 = __shfl_xor(lm, o);
                float s2 = __shfl_xor(lsum, o);
                if (m2 > lm) { lsum = lsum * expf(lm - m2) + s2; lm = m2; }
                else         { lsum += s2 * expf(m2 - lm); }
            }
            if (lr == 0) { pm[rl][wc] = lm; ps[rl][wc] = lsum; }
        }
    }
    __syncthreads();
    if (tid < 256) {
        float M = -1e30f, S = 0.f;
#pragma unroll
        for (int x = 0; x < 2; ++x) {
            float m_ = pm[tid][x], s_ = ps[tid][x];
            if (m_ > M) { S = S * expf(M - m_) + s_; M = m_; }
            else        { S += s_ * expf(m_ - M); }
        }
        int rg = row0 + tid;
        if (rg < 4032) {
            pmax[(size_t)blockIdx.x * 4032 + rg] = M;
            psum[(size_t)blockIdx.x * 4032 + rg] = S;
        }
    }
}

// ---------------- merge partials per row (4-way col-split, 256 thr); coalesced
__global__ __launch_bounds__(256) void k_merge(
    const float* __restrict__ pmax, const float* __restrict__ psum,
    const float* __restrict__ tgtl, const int* __restrict__ trg,
    float* __restrict__ blk) {
    __shared__ float pmm[4][64];
    __shared__ float pss[4][64];
    int tid = threadIdx.x;
    int r = tid & 63, q = tid >> 6;
    int row = blockIdx.x * 64 + r;
    int c0 = q * 63, c1 = (q < 3) ? (c0 + 63) : 250;
    float M = -1e30f, S = 0.f;
    for (int c = c0; c < c1; ++c) {
        float m = pmax[(size_t)c * 4032 + row], s = psum[(size_t)c * 4032 + row];
        if (m > M) { S = S * expf(M - m) + s; M = m; }
        else       { S += s * expf(m - M); }
    }
    pmm[q][r] = M;
    pss[q][r] = S;
    __syncthreads();
    if (tid < 64) {
        float M2 = -1e30f, S2 = 0.f;
        for (int q2 = 0; q2 < 4; ++q2) {
            float m = pmm[q2][tid], s = pss[q2][tid];
            if (m > M2) { S2 = S2 * expf(M2 - m) + s; M2 = m; }
            else        { S2 += s * expf(m - M2); }
        }
        int row2 = blockIdx.x * 64 + tid;
        float lse = M2 + logf(S2);
        int tdec = row2 >> 6, b = row2 & 63;
        int tgt = trg[b * TT + tdec + 1];
        float valid = (tgt != 0) ? 1.f : 0.f;
        float ce = (lse - tgtl[row2]) * valid;
        float vs = valid;
        for (int o = 32; o > 0; o >>= 1) {
            ce += __shfl_down(ce, o);
            vs += __shfl_down(vs, o);
        }
        if (tid == 0) {
            blk[blockIdx.x * 2] = ce;
            blk[blockIdx.x * 2 + 1] = vs;
        }
    }
}

__global__ void k_final(const float* __restrict__ blk, float* __restrict__ out) {
    float s0 = 0.f, s1 = 0.f;
    for (int i = 0; i < 63; ++i) { s0 += blk[2 * i]; s1 += blk[2 * i + 1]; }
    out[0] = s0 / s1;
}

extern "C" void kernel_launch(void* const* d_in, const int* in_sizes, int n_in,
                              void* d_out, int out_size, void* d_ws, size_t ws_size,
                              hipStream_t stream) {
    const int* src = (const int*)d_in[0];
    const int* trg = (const int*)d_in[1];
    const float* emb_cn = (const float*)d_in[2];
    const float* Wf = (const float*)d_in[3];
    const float* Uf = (const float*)d_in[4];
    const float* bf = (const float*)d_in[5];
    const float* Wb = (const float*)d_in[6];
    const float* Ub = (const float*)d_in[7];
    const float* bb = (const float*)d_in[8];
    const float* Wm = (const float*)d_in[9];
    const float* Um = (const float*)d_in[10];
    const float* bm = (const float*)d_in[11];
    const float* Wt = (const float*)d_in[12];
    const float* Ut = (const float*)d_in[13];
    const float* bt = (const float*)d_in[14];
    const float* emb_en = (const float*)d_in[15];
    const float* aW1 = (const float*)d_in[16];
    const float* ab1 = (const float*)d_in[17];
    const float* aW2 = (const float*)d_in[18];
    const float* ab2 = (const float*)d_in[19];
    const float* aV = (const float*)d_in[20];
    const float* abV = (const float*)d_in[21];
    const float* Wd = (const float*)d_in[22];
    const float* bd = (const float*)d_in[24];
    const float* fcW = (const float*)d_in[25];
    const float* fcb = (const float*)d_in[26];
    float* ws = (float*)d_ws;
    float* out = (float*)d_out;

    // workspace layout (floats), lifetimes re-verified:
    float* X_EMB = ws;                    // 1,048,576 (dead after f/b x-gate gemms)
    float* XG    = ws + 1048576;          // 6,291,456 (m gates)
    float* X2    = ws + 7340032;          // 4,194,304
    float* XGB   = ws + 11534336;         // 6,291,456 (aliases Y3/ENC, dead during f||b)
    float* Y3    = ws + 11534336;         // 2,097,152
    float* ENC   = ws + 13631488;         // 2,097,152 (live thru decoder: h0)
    float* TGTL  = ws + 20004864;         // 4,032
    float* BLK   = ws + 20008896;         // 126
    float* ZB    = ws + 20009088;         // 1,536 zero-bias
    // phase aliases:
    float* XTOK  = ws;                    // 1,048,576 (X_EMB dead; read only pre-decoder)
    _Float16* ENCWH = (_Float16*)(ws + 1048576);   // 3,145,728 slots (XG dead after m||t)
    _Float16* AW2T  = (_Float16*)(ws + 4194304);   // 131,072 slots (aW2^T f16)
    _Float16* EMBWH = (_Float16*)(ws + 7340032);   // 3,145,728 slots (X2+Y3 dead after enc)
    _Float16* ENCWT = (_Float16*)(ws + 10485760);  // 3,145,728 slots, ends 13,631,488 (=ENC)
    _Float16* KEYSH = (_Float16*)(ws + 15728640);  // KEYS slot; live thru decoder
    _Float16* HMATH = (_Float16*)ws;      // 2,064,384 halfs (XTOK dead before decoder writes)
    float* PMAX  = ws + 1048576;          // 1,008,000 (ENCWH dead at CE time)
    float* PSUM  = ws + 2056576;          // 1,008,000 (ends 3,064,576)
    _Float16* FCWT = (_Float16*)(ws + 7340032);    // fcW^T f16 (EMBWH/ENCWT dead at CE)

    k_embed<<<4096, 256, 0, stream>>>(src, emb_cn, X_EMB);

    // x-gates for f and b (independent), then run both layers in lockstep
    k_gemm128_bias<<<dim3(12, 32), 256, 0, stream>>>(X_EMB, Wf, bf, XG, 1536, 256);
    k_gemm128_bias<<<dim3(12, 32), 256, 0, stream>>>(X_EMB, Wb, bb, XGB, 1536, 256);
    for (int s = 0; s < 64; ++s) {
        GruP pf{XG, s ? X2 : nullptr, X2, Uf, bf + H3, s, s - 1, 1024, 0};
        GruP pb{XGB, s ? X2 : nullptr, X2, Ub, bb + H3, 63 - s, 64 - s, 1024, 512};
        k_gru5<<<512, 512, 0, stream>>>(pf, pb, src, 256);
    }
    // layer m x-gates, then pipelined m || t wavefront (t-layer xg fused on the fly)
    k_gemm128_bias<<<dim3(12, 32), 256, 0, stream>>>(X2, Wm, bm, XG, 1536, 1024);
    for (int s = 0; s <= 64; ++s) {
        EncP pm_{XG, nullptr, nullptr, nullptr, Y3, Um, bm + H3,
                 (s <= 63) ? s : -1, 512, 0};
        EncP pt_{nullptr, Y3, Wt, bt, ENC, Ut, bt + H3,
                 s - 1, 512, 0};
        k_enc_step<<<512, 512, 0, stream>>>(pm_, pt_, src);
    }
    // decoder operand precompute (all f16): KEYSH, ENCWH->ENCWT, EMBWH, AW2T
    k_gemm128_bias_h<<<dim3(4, 32), 256, 0, stream>>>(ENC, aW1, ab1, KEYSH, 512, 512);
    k_zero1536<<<6, 256, 0, stream>>>(ZB);
    k_embtok<<<4096, 256, 0, stream>>>(trg, emb_en, XTOK);
    k_gemm128_bias_h<<<dim3(12, 32), 256, 0, stream>>>(ENC, Wd, ZB, ENCWH, 1536, 512);
    k_gemm128_bias_h<<<dim3(12, 32), 256, 0, stream>>>(XTOK, Wd + (size_t)512 * H3, bd, EMBWH,
                                                       1536, 256);
    k_cvt_t<<<dim3(8, 8), 256, 0, stream>>>(aW2, AW2T, 512);
    k_trans_encw<<<dim3(24, 64), 256, 0, stream>>>(ENCWH, ENCWT);

    // decoder: ALL 63 steps in one launch (lane-cooperative coalesced reads)
    k_dec_all3<<<64, 512, 0, stream>>>(KEYSH, ENC, AW2T, ab2, aV, abV,
                                       ENCWT, EMBWH, bd + H3, HMATH);

    // fcW -> f16 transpose (into dead EMBWH/ENCWT space), then MFMA logits + CE
    k_cvt_t<<<dim3(500, 8), 256, 0, stream>>>(fcW, FCWT, VV);
    k_gemm256_ce_m<<<dim3(250, 16), 512, 0, stream>>>(HMATH, FCWT, fcb, trg,
                                                      PMAX, PSUM, TGTL);
    k_merge<<<63, 256, 0, stream>>>(PMAX, PSUM, TGTL, trg, BLK);
    k_final<<<1, 1, 0, stream>>>(BLK, out);
}

// Round 18
// 3702.171 us; speedup vs baseline: 1.7838x; 1.7838x over previous
//
#include <hip/hip_runtime.h>
#include <math.h>

#define HH 512
#define EE 256
#define BB 64
#define TT 64
#define VV 32000
#define H3 1536
#define TDEC 63

typedef _Float16 v2h __attribute__((ext_vector_type(2)));
typedef _Float16 v4h __attribute__((ext_vector_type(4)));
typedef _Float16 v8h __attribute__((ext_vector_type(8)));
typedef float v4f __attribute__((ext_vector_type(4)));

__device__ __forceinline__ float sigm(float x) { return 1.f / (1.f + expf(-x)); }

// ---------------- embedding gather: x[b*T+t][e] = emb[src[b*T+t]][e]
__global__ void k_embed(const int* __restrict__ src, const float* __restrict__ emb,
                        float* __restrict__ x) {
    int idx = blockIdx.x * 256 + threadIdx.x;      // B*T*E = 1048576
    int row = idx >> 8;
    int e = idx & 255;
    x[idx] = emb[src[row] * EE + e];
}

// ---------------- decoder-token embedding gather: XTOK[t*64+b] = emb_en[tok(b,t)]
__global__ void k_embtok(const int* __restrict__ trg, const float* __restrict__ emb,
                         float* __restrict__ x) {
    int idx = blockIdx.x * 256 + threadIdx.x;      // 4096*256 = 1048576
    int row = idx >> 8;
    int e = idx & 255;
    int t = row >> 6, b = row & 63;
    int tok = (t == 0) ? 1 : ((t < 63) ? trg[b * TT + t] : 0);
    x[idx] = emb[tok * EE + e];
}

__global__ void k_zero1536(float* __restrict__ z) {
    int i = blockIdx.x * 256 + threadIdx.x;
    if (i < 1536) z[i] = 0.f;
}

// ---------------- fp32 -> f16 pack (float4 -> 2x v2h per thread)
__global__ void k_cvt_h(const float4* __restrict__ src, v2h* __restrict__ dst) {
    int i = blockIdx.x * 256 + threadIdx.x;
    float4 v = src[i];
    v2h a = {(_Float16)v.x, (_Float16)v.y};
    v2h b = {(_Float16)v.z, (_Float16)v.w};
    dst[2 * i] = a;
    dst[2 * i + 1] = b;
}

// ---------------- W (512 x N fp32) -> WT (N x 512 f16), 64x64 LDS tile transpose
__global__ __launch_bounds__(256) void k_cvt_t(const float* __restrict__ W,
                                               _Float16* __restrict__ WT, int N) {
    __shared__ _Float16 tile[64][65];
    int n0 = blockIdx.x * 64, k0 = blockIdx.y * 64;
    int t = threadIdx.x;
#pragma unroll
    for (int i = 0; i < 16; ++i) {
        int idx = i * 256 + t;
        int r = idx >> 6, c = idx & 63;     // r = k-local, c = n-local
        tile[r][c] = (_Float16)W[(size_t)(k0 + r) * N + n0 + c];
    }
    __syncthreads();
#pragma unroll
    for (int i = 0; i < 16; ++i) {
        int idx = i * 256 + t;
        int r = idx >> 6, c = idx & 63;     // r = n-local, c = k-local
        WT[(size_t)(n0 + r) * 512 + k0 + c] = tile[c][r];
    }
}

// ---------------- 128x128 fp32 GEMM + bias, 8x8 micro-tile (split 64+64), R5-proven
__global__ __launch_bounds__(256) void k_gemm128_bias(
    const float* __restrict__ A, const float* __restrict__ W,
    const float* __restrict__ bias, float* __restrict__ C,
    int N, int K) {
    __shared__ float As[8][128];
    __shared__ float Bs[8][128];
    int row0 = blockIdx.y * 128, col0 = blockIdx.x * 128;
    int tid = threadIdx.x;
    int tx = tid & 15, ty = tid >> 4;
    int ar = tid >> 1, aq = tid & 1;
    int bkk = tid >> 5, bc4 = tid & 31;
    float acc[2][2][4][4] = {};
    for (int k0 = 0; k0 < K; k0 += 8) {
        float4 av = *(const float4*)&A[(size_t)(row0 + ar) * K + k0 + aq * 4];
        float4 bv = *(const float4*)&W[(size_t)(k0 + bkk) * N + col0 + bc4 * 4];
        As[aq * 4 + 0][ar] = av.x;
        As[aq * 4 + 1][ar] = av.y;
        As[aq * 4 + 2][ar] = av.z;
        As[aq * 4 + 3][ar] = av.w;
        *(float4*)&Bs[bkk][bc4 * 4] = bv;
        __syncthreads();
#pragma unroll
        for (int kk = 0; kk < 8; ++kk) {
            float4 a0 = *(const float4*)&As[kk][ty * 4];
            float4 a1 = *(const float4*)&As[kk][64 + ty * 4];
            float4 b0 = *(const float4*)&Bs[kk][tx * 4];
            float4 b1 = *(const float4*)&Bs[kk][64 + tx * 4];
            float a_[2][4] = {{a0.x, a0.y, a0.z, a0.w}, {a1.x, a1.y, a1.z, a1.w}};
            float b_[2][4] = {{b0.x, b0.y, b0.z, b0.w}, {b1.x, b1.y, b1.z, b1.w}};
#pragma unroll
            for (int rh = 0; rh < 2; ++rh)
#pragma unroll
                for (int i = 0; i < 4; ++i)
#pragma unroll
                    for (int ch = 0; ch < 2; ++ch)
#pragma unroll
                        for (int j = 0; j < 4; ++j)
                            acc[rh][ch][i][j] = fmaf(a_[rh][i], b_[ch][j], acc[rh][ch][i][j]);
        }
        __syncthreads();
    }
#pragma unroll
    for (int rh = 0; rh < 2; ++rh)
#pragma unroll
        for (int i = 0; i < 4; ++i) {
            int row = row0 + rh * 64 + ty * 4 + i;
#pragma unroll
            for (int ch = 0; ch < 2; ++ch) {
                int c = col0 + ch * 64 + tx * 4;
                float4 bv = *(const float4*)&bias[c];
                float4 o;
                o.x = acc[rh][ch][i][0] + bv.x;
                o.y = acc[rh][ch][i][1] + bv.y;
                o.z = acc[rh][ch][i][2] + bv.z;
                o.w = acc[rh][ch][i][3] + bv.w;
                *(float4*)&C[(size_t)row * N + c] = o;
            }
        }
}

// ---------------- same GEMM, f16 output (for decoder operand precompute)
__global__ __launch_bounds__(256) void k_gemm128_bias_h(
    const float* __restrict__ A, const float* __restrict__ W,
    const float* __restrict__ bias, _Float16* __restrict__ C,
    int N, int K) {
    __shared__ float As[8][128];
    __shared__ float Bs[8][128];
    int row0 = blockIdx.y * 128, col0 = blockIdx.x * 128;
    int tid = threadIdx.x;
    int tx = tid & 15, ty = tid >> 4;
    int ar = tid >> 1, aq = tid & 1;
    int bkk = tid >> 5, bc4 = tid & 31;
    float acc[2][2][4][4] = {};
    for (int k0 = 0; k0 < K; k0 += 8) {
        float4 av = *(const float4*)&A[(size_t)(row0 + ar) * K + k0 + aq * 4];
        float4 bv = *(const float4*)&W[(size_t)(k0 + bkk) * N + col0 + bc4 * 4];
        As[aq * 4 + 0][ar] = av.x;
        As[aq * 4 + 1][ar] = av.y;
        As[aq * 4 + 2][ar] = av.z;
        As[aq * 4 + 3][ar] = av.w;
        *(float4*)&Bs[bkk][bc4 * 4] = bv;
        __syncthreads();
#pragma unroll
        for (int kk = 0; kk < 8; ++kk) {
            float4 a0 = *(const float4*)&As[kk][ty * 4];
            float4 a1 = *(const float4*)&As[kk][64 + ty * 4];
            float4 b0 = *(const float4*)&Bs[kk][tx * 4];
            float4 b1 = *(const float4*)&Bs[kk][64 + tx * 4];
            float a_[2][4] = {{a0.x, a0.y, a0.z, a0.w}, {a1.x, a1.y, a1.z, a1.w}};
            float b_[2][4] = {{b0.x, b0.y, b0.z, b0.w}, {b1.x, b1.y, b1.z, b1.w}};
#pragma unroll
            for (int rh = 0; rh < 2; ++rh)
#pragma unroll
                for (int i = 0; i < 4; ++i)
#pragma unroll
                    for (int ch = 0; ch < 2; ++ch)
#pragma unroll
                        for (int j = 0; j < 4; ++j)
                            acc[rh][ch][i][j] = fmaf(a_[rh][i], b_[ch][j], acc[rh][ch][i][j]);
        }
        __syncthreads();
    }
#pragma unroll
    for (int rh = 0; rh < 2; ++rh)
#pragma unroll
        for (int i = 0; i < 4; ++i) {
            int row = row0 + rh * 64 + ty * 4 + i;
#pragma unroll
            for (int ch = 0; ch < 2; ++ch) {
                int c = col0 + ch * 64 + tx * 4;
                float4 bv = *(const float4*)&bias[c];
                v4h o;
                o[0] = (_Float16)(acc[rh][ch][i][0] + bv.x);
                o[1] = (_Float16)(acc[rh][ch][i][1] + bv.y);
                o[2] = (_Float16)(acc[rh][ch][i][2] + bv.z);
                o[3] = (_Float16)(acc[rh][ch][i][3] + bv.w);
                *(v4h*)&C[(size_t)row * N + c] = o;
            }
        }
}

// ---------------- GRU recurrent step, 4-batch-shared / 256-block / split-k-16 (R7-proven)
struct GruP {
    const float* xg;     // (B*T, 3H)
    const float* hb;     // carried h base (nullptr -> zeros)
    float* y;
    const float* U;      // (H, 3H)
    const float* b1;     // (3H)
    int t, tprev, ystride, yoff;
};

__global__ __launch_bounds__(512) void k_gru5(GruP p0, GruP p1, const int* __restrict__ src,
                                              int nblk) {
    GruP p = (blockIdx.x < nblk) ? p0 : p1;
    int blk = (blockIdx.x < nblk) ? blockIdx.x : blockIdx.x - nblk;
    int bg = blk >> 4;                 // batches bg*4 .. bg*4+3
    int ic = blk & 15;                 // 32-col chunk
    int tid = threadIdx.x;
    int c = tid & 31, kh = tid >> 5;   // kh 0..15, each owns 32 k
    int i = ic * 32 + c;
    __shared__ float hs[4][512];
    __shared__ float ps[12][512];      // [gate*4+b][kh*32+c] (transposed: conflict-free)
    for (int j = tid; j < 2048; j += 512) {
        int bl = j >> 9, k = j & 511;
        hs[bl][k] = p.hb ? p.hb[(size_t)((bg * 4 + bl) * TT + p.tprev) * p.ystride + p.yoff + k]
                         : 0.f;
    }
    __syncthreads();
    float az[4] = {}, ar[4] = {}, ah[4] = {};
    const float* Up = p.U + (size_t)(kh * 32) * H3 + i;
    int ks0 = kh * 32;
#pragma unroll 8
    for (int k = 0; k < 32; ++k) {
        const float* Ur = Up + k * H3;
        float uz = Ur[0], ur = Ur[512], uh = Ur[1024];
#pragma unroll
        for (int b = 0; b < 4; ++b) {
            float h = hs[b][ks0 + k];                 // LDS broadcast within kh-group
            az[b] = fmaf(h, uz, az[b]);
            ar[b] = fmaf(h, ur, ar[b]);
            ah[b] = fmaf(h, uh, ah[b]);
        }
    }
#pragma unroll
    for (int b = 0; b < 4; ++b) {
        ps[b][tid] = az[b];
        ps[4 + b][tid] = ar[b];
        ps[8 + b][tid] = ah[b];
    }
    __syncthreads();
    if (tid < 128) {
        int b = tid >> 5, cc = tid & 31;
        float AZ = 0.f, AR = 0.f, AH = 0.f;
        for (int q = 0; q < 16; ++q) {
            AZ += ps[b][q * 32 + cc];
            AR += ps[4 + b][q * 32 + cc];
            AH += ps[8 + b][q * 32 + cc];
        }
        int ii = ic * 32 + cc;
        int row = (bg * 4 + b) * TT + p.t;
        const float* xr = p.xg + (size_t)row * H3;
        float z = sigm(xr[ii] + AZ + p.b1[ii]);
        float r = sigm(xr[512 + ii] + AR + p.b1[512 + ii]);
        float hc = sigm(xr[1024 + ii] + r * (AH + p.b1[1024 + ii]));
        float hp = hs[b][ii];
        float hn = (src[row] != 0) ? (z * hp + (1.f - z) * hc) : hp;
        p.y[(size_t)row * p.ystride + p.yoff + ii] = hn;
    }
}

// ---------------- pipelined encoder step: m-phase (xg precomputed) || t-phase (xg fused)
struct EncP {
    const float* xg;     // m-phase: precomputed gates; t-phase: nullptr (fused)
    const float* xseq;   // t-phase: input sequence (B*T, 512)
    const float* xW;     // t-phase: W (512, 3H)
    const float* xb0;    // t-phase: x-bias (row 0 of b)
    float* y;            // output sequence
    const float* U;      // (H, 3H)
    const float* b1;     // recurrent bias (row 1)
    int t;               // timestep this stage (-1 = inactive)
    int ystride, yoff;
};

__global__ __launch_bounds__(512) void k_enc_step(EncP pm, EncP pt, const int* __restrict__ src) {
    EncP p = (blockIdx.x < 256) ? pm : pt;
    if (p.t < 0) return;
    int blk = blockIdx.x & 255;
    int bg = blk >> 4, ic = blk & 15;
    int tid = threadIdx.x;
    int c = tid & 31, kh = tid >> 5;
    int i = ic * 32 + c;
    __shared__ float hs[4][512];
    __shared__ float xs[4][512];
    __shared__ float ps[16][512];
    bool fused = (p.xg == nullptr);
    int tprev = p.t - 1;
    for (int j = tid; j < 2048; j += 512) {
        int bl = j >> 9, k = j & 511;
        hs[bl][k] = (tprev < 0) ? 0.f
            : p.y[(size_t)((bg * 4 + bl) * TT + tprev) * p.ystride + p.yoff + k];
        if (fused)
            xs[bl][k] = p.xseq[(size_t)((bg * 4 + bl) * TT + p.t) * 512 + k];
    }
    __syncthreads();
    float az[4] = {}, ar[4] = {}, ahU[4] = {}, ahW[4] = {};
    int ks0 = kh * 32;
    {
        const float* Up = p.U + (size_t)ks0 * H3 + i;
#pragma unroll 8
        for (int k = 0; k < 32; ++k) {
            const float* Ur = Up + k * H3;
            float uz = Ur[0], ur = Ur[512], uh = Ur[1024];
#pragma unroll
            for (int b = 0; b < 4; ++b) {
                float h = hs[b][ks0 + k];
                az[b] = fmaf(h, uz, az[b]);
                ar[b] = fmaf(h, ur, ar[b]);
                ahU[b] = fmaf(h, uh, ahU[b]);
            }
        }
    }
    if (fused) {
        const float* Wp = p.xW + (size_t)ks0 * H3 + i;
#pragma unroll 8
        for (int k = 0; k < 32; ++k) {
            const float* Wr = Wp + k * H3;
            float wz = Wr[0], wr = Wr[512], wh = Wr[1024];
#pragma unroll
            for (int b = 0; b < 4; ++b) {
                float x = xs[b][ks0 + k];
                az[b] = fmaf(x, wz, az[b]);
                ar[b] = fmaf(x, wr, ar[b]);
                ahW[b] = fmaf(x, wh, ahW[b]);
            }
        }
    }
#pragma unroll
    for (int b = 0; b < 4; ++b) {
        ps[b][tid] = az[b];
        ps[4 + b][tid] = ar[b];
        ps[8 + b][tid] = ahU[b];
        ps[12 + b][tid] = ahW[b];
    }
    __syncthreads();
    if (tid < 128) {
        int b = tid >> 5, cc = tid & 31;
        float AZ = 0.f, AR = 0.f, AHU = 0.f, AHW = 0.f;
        for (int q = 0; q < 16; ++q) {
            AZ += ps[b][q * 32 + cc];
            AR += ps[4 + b][q * 32 + cc];
            AHU += ps[8 + b][q * 32 + cc];
            AHW += ps[12 + b][q * 32 + cc];
        }
        int ii = ic * 32 + cc;
        int row = (bg * 4 + b) * TT + p.t;
        float xz, xr_, xh;
        if (fused) {
            xz = p.xb0[ii];
            xr_ = p.xb0[512 + ii];
            xh = AHW + p.xb0[1024 + ii];
        } else {
            const float* xr = p.xg + (size_t)row * H3;
            xz = xr[ii];
            xr_ = xr[512 + ii];
            xh = xr[1024 + ii];
        }
        float z = sigm(xz + AZ + p.b1[ii]);
        float r = sigm(xr_ + AR + p.b1[512 + ii]);
        float hc = sigm(xh + r * (AHU + p.b1[1024 + ii]));
        float hp = hs[b][ii];
        float hn = (src[row] != 0) ? (z * hp + (1.f - z) * hc) : hp;
        p.y[(size_t)row * p.ystride + p.yoff + ii] = hn;
    }
}

// ---------------- decoder, ALL 63 steps; per-thread outputs, vector+coalesced loads,
// split-k via LDS (k_gru5 recipe). block = batch, 512 threads.
__global__ __launch_bounds__(512) void k_dec_all4(
    const _Float16* __restrict__ keysh, const float* __restrict__ enc,
    const _Float16* __restrict__ aW2h,   // (512 k, 512 n) f16, k-major
    const float* __restrict__ ab2, const float* __restrict__ aV,
    const float* __restrict__ abV,
    const _Float16* __restrict__ ENCWh,  // (b*64+s, 1536) f16
    const _Float16* __restrict__ EMBWh,
    const float* __restrict__ b1, _Float16* __restrict__ HMATH) {
    int b = blockIdx.x;
    int tid = threadIdx.x;
    __shared__ float hsh[HH];
    __shared__ float qs[HH];
    __shared__ float sc[TT];
    __shared__ float ps[4][HH];
    hsh[tid] = enc[((size_t)(b * TT + 63)) * HH + tid];   // h0 = enc[b][T-1]
    __syncthreads();
    float bz = b1[tid], br_ = b1[512 + tid], bh = b1[1024 + tid];
    int ng = tid & 127, kh = tid >> 7;     // phase A: n = ng*4, k in [kh*128, +128)
    const v4h* WqA = (const v4h*)(aW2h + (size_t)(kh * 128) * HH) + ng;
    const float* hpA = hsh + kh * 128;
    for (int t = 0; t < TDEC; ++t) {
        // ---- phase A: q = h @ aW2 (v4h coalesced, 4-way split-k, LDS reduce)
        {
            v4f acc = {0.f, 0.f, 0.f, 0.f};
#pragma unroll 16
            for (int k = 0; k < 128; ++k) {
                v4h w = WqA[(size_t)k * 128];
                float h = hpA[k];
                acc[0] = fmaf(h, (float)w[0], acc[0]);
                acc[1] = fmaf(h, (float)w[1], acc[1]);
                acc[2] = fmaf(h, (float)w[2], acc[2]);
                acc[3] = fmaf(h, (float)w[3], acc[3]);
            }
            *(v4f*)&ps[kh][ng * 4] = acc;
        }
        __syncthreads();
        qs[tid] = ps[0][tid] + ps[1][tid] + ps[2][tid] + ps[3][tid] + ab2[tid];
        __syncthreads();
        // ---- phase B: scores, 8 parts x 64 h, vectorized keys reads (R16-proven)
        {
            int s = tid >> 3, part = tid & 7;
            const v8h* kr = (const v8h*)(keysh + (size_t)(b * TT + s) * HH + part * 64);
            const float* qp = qs + part * 64;
            const float* avp = aV + part * 64;
            float p = 0.f;
#pragma unroll
            for (int h8 = 0; h8 < 8; ++h8) {
                v8h kv = kr[h8];
#pragma unroll
                for (int u = 0; u < 8; ++u)
                    p += tanhf((float)kv[u] + qp[h8 * 8 + u]) * avp[h8 * 8 + u];
            }
            p += __shfl_down(p, 1);
            p += __shfl_down(p, 2);
            p += __shfl_down(p, 4);
            if (part == 0) sc[s] = p + abV[0];
        }
        __syncthreads();
        if (tid < 64) {
            float v = sc[tid];
            float m = v;
            for (int o = 1; o < 64; o <<= 1) m = fmaxf(m, __shfl_xor(m, o));
            float e = expf(v - m);
            float su = e;
            for (int o = 1; o < 64; o <<= 1) su += __shfl_xor(su, o);
            sc[tid] = e / su;
        }
        __syncthreads();
        // ---- phase C: pre-acts via lane-coalesced ENCWh columns (3 streams, unroll 8)
        {
            const _Float16* EW = ENCWh + (size_t)(b * TT) * H3;
            float p0 = 0.f, p1 = 0.f, p2 = 0.f;
#pragma unroll 8
            for (int s = 0; s < TT; ++s) {
                float w = sc[s];
                const _Float16* er = EW + (size_t)s * H3;
                p0 = fmaf(w, (float)er[tid], p0);
                p1 = fmaf(w, (float)er[512 + tid], p1);
                p2 = fmaf(w, (float)er[1024 + tid], p2);
            }
            const _Float16* mr = EMBWh + (size_t)(t * BB + b) * H3;
            float z = sigm(p0 + (float)mr[tid] + bz);
            float r = sigm(p1 + (float)mr[512 + tid] + br_);
            float hc = sigm(p2 + (float)mr[1024 + tid] + r * bh);
            float hn = (1.f - z) * hc;
            HMATH[((size_t)t * BB + b) * HH + tid] = (_Float16)hn;
            hsh[tid] = hn;
        }
        __syncthreads();
    }
}

// ---------------- logits GEMM via MFMA f16, 256x128 tile, XOR-swizzled LDS + fused LSE
__global__ __launch_bounds__(512) void k_gemm256_ce_m(
    const _Float16* __restrict__ Ah, const _Float16* __restrict__ WT,
    const float* __restrict__ bias, const int* __restrict__ trg,
    float* __restrict__ pmax, float* __restrict__ psum, float* __restrict__ tgtl) {
    __shared__ v2h As[256][20];     // 4 chunks of 16B per row, XOR-swizzled by row&3
    __shared__ v2h Bs[128][20];
    __shared__ float pm[256][2];
    __shared__ float ps[256][2];
    const v2h* A2 = (const v2h*)Ah;
    const v2h* W2 = (const v2h*)WT;
    int row0 = blockIdx.y * 256, col0 = blockIdx.x * 128;
    int tid = threadIdx.x;
    int l = tid & 63, wv = tid >> 6;
    int wr = wv >> 1, wc = wv & 1;           // 4 wave-rows x 2 wave-cols
    int lr = l & 15, kb = l >> 4;            // frag lane, k-block
    int sr = tid >> 1, sh = tid & 1;         // A staging: row 0..255, half
    int br = (tid & 255) >> 1, bh = tid & 1; // B staging (tid<256): row 0..127, half
    int arow = row0 + sr;
    if (arow > 4031) arow = 4031;            // clamp pad rows
    v4f acc[4][4];
#pragma unroll
    for (int i = 0; i < 4; ++i)
#pragma unroll
        for (int j = 0; j < 4; ++j) acc[i][j] = (v4f){0.f, 0.f, 0.f, 0.f};
    for (int k0 = 0; k0 < 256; k0 += 16) {   // k0 in v2h units; 32 f16 per step
        const v8h* agp = (const v8h*)(A2 + (size_t)arow * 256 + k0 + sh * 8);
        v8h av0 = agp[0], av1 = agp[1];
        v8h bv0, bv1;
        if (tid < 256) {
            const v8h* bgp = (const v8h*)(W2 + (size_t)(col0 + br) * 256 + k0 + bh * 8);
            bv0 = bgp[0];
            bv1 = bgp[1];
        }
        __syncthreads();                     // prev-iter fragment reads done
        int ca0 = (sh * 2) ^ (sr & 3), ca1 = (sh * 2 + 1) ^ (sr & 3);
        *(v8h*)&As[sr][ca0 * 4] = av0;
        *(v8h*)&As[sr][ca1 * 4] = av1;
        if (tid < 256) {
            int cb0 = (bh * 2) ^ (br & 3), cb1 = (bh * 2 + 1) ^ (br & 3);
            *(v8h*)&Bs[br][cb0 * 4] = bv0;
            *(v8h*)&Bs[br][cb1 * 4] = bv1;
        }
        __syncthreads();
        v8h af[4], bf[4];
#pragma unroll
        for (int f = 0; f < 4; ++f) {
            int ra = wr * 64 + f * 16 + lr;
            int rb = wc * 64 + f * 16 + lr;
            af[f] = *(const v8h*)&As[ra][(kb ^ (ra & 3)) * 4];
            bf[f] = *(const v8h*)&Bs[rb][(kb ^ (rb & 3)) * 4];
        }
#pragma unroll
        for (int fr = 0; fr < 4; ++fr)
#pragma unroll
            for (int fc = 0; fc < 4; ++fc)
                acc[fr][fc] = __builtin_amdgcn_mfma_f32_16x16x32_f16(
                    af[fr], bf[fc], acc[fr][fc], 0, 0, 0);
    }
    // epilogue: C/D map col=lane&15, row=(lane>>4)*4+reg (guide-verified)
    float bv[4];
#pragma unroll
    for (int fc = 0; fc < 4; ++fc) bv[fc] = bias[col0 + wc * 64 + fc * 16 + lr];
#pragma unroll
    for (int fr = 0; fr < 4; ++fr) {
#pragma unroll
        for (int ri = 0; ri < 4; ++ri) {
            int rl = wr * 64 + fr * 16 + kb * 4 + ri;
            int rg = row0 + rl;
            int tdec = rg >> 6, bq = rg & 63;
            int tgt = (rg < 4032) ? trg[bq * TT + tdec + 1] : -1;
            float vv[4];
            float lm = -1e30f;
#pragma unroll
            for (int fc = 0; fc < 4; ++fc) {
                int c = col0 + wc * 64 + fc * 16 + lr;
                float v = acc[fr][fc][ri] + bv[fc];
                vv[fc] = v;
                lm = fmaxf(lm, v);
                if (c == tgt) tgtl[rg] = v;
            }
            float lsum = 0.f;
#pragma unroll
            for (int fc = 0; fc < 4; ++fc) lsum += expf(vv[fc] - lm);
            // online-merge across the 16 col-lanes (same rows)
            for (int o = 1; o < 16; o <<= 1) {
                float m2 = __shfl_xor(lm, o);
                float s2 = __shfl_xor(lsum, o);
                if (m2 > lm) { lsum = lsum * expf(lm - m2) + s2; lm = m2; }
                else         { lsum += s2 * expf(m2 - lm); }
            }
            if (lr == 0) { pm[rl][wc] = lm; ps[rl][wc] = lsum; }
        }
    }
    __syncthreads();
    if (tid < 256) {
        float M = -1e30f, S = 0.f;
#pragma unroll
        for (int x = 0; x < 2; ++x) {
            float m_ = pm[tid][x], s_ = ps[tid][x];
            if (m_ > M) { S = S * expf(M - m_) + s_; M = m_; }
            else        { S += s_ * expf(m_ - M); }
        }
        int rg = row0 + tid;
        if (rg < 4032) {
            pmax[(size_t)blockIdx.x * 4032 + rg] = M;
            psum[(size_t)blockIdx.x * 4032 + rg] = S;
        }
    }
}

// ---------------- merge partials per row (4-way col-split, 256 thr); coalesced
__global__ __launch_bounds__(256) void k_merge(
    const float* __restrict__ pmax, const float* __restrict__ psum,
    const float* __restrict__ tgtl, const int* __restrict__ trg,
    float* __restrict__ blk) {
    __shared__ float pmm[4][64];
    __shared__ float pss[4][64];
    int tid = threadIdx.x;
    int r = tid & 63, q = tid >> 6;
    int row = blockIdx.x * 64 + r;
    int c0 = q * 63, c1 = (q < 3) ? (c0 + 63) : 250;
    float M = -1e30f, S = 0.f;
    for (int c = c0; c < c1; ++c) {
        float m = pmax[(size_t)c * 4032 + row], s = psum[(size_t)c * 4032 + row];
        if (m > M) { S = S * expf(M - m) + s; M = m; }
        else       { S += s * expf(m - M); }
    }
    pmm[q][r] = M;
    pss[q][r] = S;
    __syncthreads();
    if (tid < 64) {
        float M2 = -1e30f, S2 = 0.f;
        for (int q2 = 0; q2 < 4; ++q2) {
            float m = pmm[q2][tid], s = pss[q2][tid];
            if (m > M2) { S2 = S2 * expf(M2 - m) + s; M2 = m; }
            else        { S2 += s * expf(m - M2); }
        }
        int row2 = blockIdx.x * 64 + tid;
        float lse = M2 + logf(S2);
        int tdec = row2 >> 6, b = row2 & 63;
        int tgt = trg[b * TT + tdec + 1];
        float valid = (tgt != 0) ? 1.f : 0.f;
        float ce = (lse - tgtl[row2]) * valid;
        float vs = valid;
        for (int o = 32; o > 0; o >>= 1) {
            ce += __shfl_down(ce, o);
            vs += __shfl_down(vs, o);
        }
        if (tid == 0) {
            blk[blockIdx.x * 2] = ce;
            blk[blockIdx.x * 2 + 1] = vs;
        }
    }
}

__global__ void k_final(const float* __restrict__ blk, float* __restrict__ out) {
    float s0 = 0.f, s1 = 0.f;
    for (int i = 0; i < 63; ++i) { s0 += blk[2 * i]; s1 += blk[2 * i + 1]; }
    out[0] = s0 / s1;
}

extern "C" void kernel_launch(void* const* d_in, const int* in_sizes, int n_in,
                              void* d_out, int out_size, void* d_ws, size_t ws_size,
                              hipStream_t stream) {
    const int* src = (const int*)d_in[0];
    const int* trg = (const int*)d_in[1];
    const float* emb_cn = (const float*)d_in[2];
    const float* Wf = (const float*)d_in[3];
    const float* Uf = (const float*)d_in[4];
    const float* bf = (const float*)d_in[5];
    const float* Wb = (const float*)d_in[6];
    const float* Ub = (const float*)d_in[7];
    const float* bb = (const float*)d_in[8];
    const float* Wm = (const float*)d_in[9];
    const float* Um = (const float*)d_in[10];
    const float* bm = (const float*)d_in[11];
    const float* Wt = (const float*)d_in[12];
    const float* Ut = (const float*)d_in[13];
    const float* bt = (const float*)d_in[14];
    const float* emb_en = (const float*)d_in[15];
    const float* aW1 = (const float*)d_in[16];
    const float* ab1 = (const float*)d_in[17];
    const float* aW2 = (const float*)d_in[18];
    const float* ab2 = (const float*)d_in[19];
    const float* aV = (const float*)d_in[20];
    const float* abV = (const float*)d_in[21];
    const float* Wd = (const float*)d_in[22];
    const float* bd = (const float*)d_in[24];
    const float* fcW = (const float*)d_in[25];
    const float* fcb = (const float*)d_in[26];
    float* ws = (float*)d_ws;
    float* out = (float*)d_out;

    // workspace layout (floats), lifetimes re-verified:
    float* X_EMB = ws;                    // 1,048,576 (dead after f/b x-gate gemms)
    float* XG    = ws + 1048576;          // 6,291,456 (m gates)
    float* X2    = ws + 7340032;          // 4,194,304
    float* XGB   = ws + 11534336;         // 6,291,456 (aliases Y3/ENC, dead during f||b)
    float* Y3    = ws + 11534336;         // 2,097,152
    float* ENC   = ws + 13631488;         // 2,097,152 (live thru decoder: h0)
    float* TGTL  = ws + 20004864;         // 4,032
    float* BLK   = ws + 20008896;         // 126
    float* ZB    = ws + 20009088;         // 1,536 zero-bias
    // phase aliases:
    float* XTOK  = ws;                    // 1,048,576 (X_EMB dead; read only pre-decoder)
    _Float16* ENCWH = (_Float16*)(ws + 1048576);   // 3,145,728 slots (XG dead after m||t)
    _Float16* AW2H  = (_Float16*)(ws + 4194304);   // 131,072 slots (aW2 f16, k-major)
    _Float16* EMBWH = (_Float16*)(ws + 7340032);   // 3,145,728 slots (X2+Y3 dead after enc)
    _Float16* KEYSH = (_Float16*)(ws + 15728640);  // KEYS slot; live thru decoder
    _Float16* HMATH = (_Float16*)ws;      // 2,064,384 halfs (XTOK dead before decoder writes)
    float* PMAX  = ws + 1048576;          // 1,008,000 (ENCWH dead at CE time)
    float* PSUM  = ws + 2056576;          // 1,008,000 (ends 3,064,576)
    _Float16* FCWT = (_Float16*)(ws + 7340032);    // fcW^T f16 (EMBWH dead at CE)

    k_embed<<<4096, 256, 0, stream>>>(src, emb_cn, X_EMB);

    // x-gates for f and b (independent), then run both layers in lockstep
    k_gemm128_bias<<<dim3(12, 32), 256, 0, stream>>>(X_EMB, Wf, bf, XG, 1536, 256);
    k_gemm128_bias<<<dim3(12, 32), 256, 0, stream>>>(X_EMB, Wb, bb, XGB, 1536, 256);
    for (int s = 0; s < 64; ++s) {
        GruP pf{XG, s ? X2 : nullptr, X2, Uf, bf + H3, s, s - 1, 1024, 0};
        GruP pb{XGB, s ? X2 : nullptr, X2, Ub, bb + H3, 63 - s, 64 - s, 1024, 512};
        k_gru5<<<512, 512, 0, stream>>>(pf, pb, src, 256);
    }
    // layer m x-gates, then pipelined m || t wavefront (t-layer xg fused on the fly)
    k_gemm128_bias<<<dim3(12, 32), 256, 0, stream>>>(X2, Wm, bm, XG, 1536, 1024);
    for (int s = 0; s <= 64; ++s) {
        EncP pm_{XG, nullptr, nullptr, nullptr, Y3, Um, bm + H3,
                 (s <= 63) ? s : -1, 512, 0};
        EncP pt_{nullptr, Y3, Wt, bt, ENC, Ut, bt + H3,
                 s - 1, 512, 0};
        k_enc_step<<<512, 512, 0, stream>>>(pm_, pt_, src);
    }
    // decoder operand precompute (all f16): KEYSH, ENCWH, EMBWH, AW2H
    k_gemm128_bias_h<<<dim3(4, 32), 256, 0, stream>>>(ENC, aW1, ab1, KEYSH, 512, 512);
    k_zero1536<<<6, 256, 0, stream>>>(ZB);
    k_embtok<<<4096, 256, 0, stream>>>(trg, emb_en, XTOK);
    k_gemm128_bias_h<<<dim3(12, 32), 256, 0, stream>>>(ENC, Wd, ZB, ENCWH, 1536, 512);
    k_gemm128_bias_h<<<dim3(12, 32), 256, 0, stream>>>(XTOK, Wd + (size_t)512 * H3, bd, EMBWH,
                                                       1536, 256);
    k_cvt_h<<<256, 256, 0, stream>>>((const float4*)aW2, (v2h*)AW2H);

    // decoder: ALL 63 steps in one launch (per-thread outputs, vector+coalesced loads)
    k_dec_all4<<<64, 512, 0, stream>>>(KEYSH, ENC, AW2H, ab2, aV, abV,
                                       ENCWH, EMBWH, bd + H3, HMATH);

    // fcW -> f16 transpose (into dead EMBWH space), then MFMA logits + CE
    k_cvt_t<<<dim3(500, 8), 256, 0, stream>>>(fcW, FCWT, VV);
    k_gemm256_ce_m<<<dim3(250, 16), 512, 0, stream>>>(HMATH, FCWT, fcb, trg,
                                                      PMAX, PSUM, TGTL);
    k_merge<<<63, 256, 0, stream>>>(PMAX, PSUM, TGTL, trg, BLK);
    k_final<<<1, 1, 0, stream>>>(BLK, out);
}